// Round 5
// baseline (505.996 us; speedup 1.0000x reference)
//
#include <hip/hip_runtime.h>
#include <math.h>

// ---------------------------------------------------------------------------
// KAN-Conv CIFAR net on gfx950, round 10.
// r9's cooperative mega-kernel never launched (output all zeros -> absmax ==
// max|ref|; hipLaunchCooperativeKernel rejected under capture / exact-fit
// occupancy). Same fusion, NO cooperative API:
//  - regular launch, 256 blocks x 512 threads = 1 block/CU guaranteed
//    co-resident (VGPR<=256 via launch_bounds(512,2), LDS 51.4KB).
//  - hand-rolled device-scope global barrier: threadfence (buffer_wbl2 sc1
//    writeback past non-coherent per-XCD L2) -> syncthreads -> leader
//    atomicAdd + acquire-spin -> syncthreads -> threadfence (invalidate,
//    also clears stale L2 lines from previous graph replay).
//  - counters in d_ws, hipMemsetAsync(64B) before launch (capturable).
//  - phases loop over 2 virtual tiles (tile = bid + 256*it); bodies are the
//    r8-proven conv configs (L1 GO=2/FS=1, L2 GO=4/FS=4, L3 GO=4/FS=8/OS=2).
// ---------------------------------------------------------------------------

#define BATCH 256
#define NBLK  256
#define NTHR  512

struct W3 { float x, y, z; };   // packed 12-byte LDS record

__device__ __forceinline__ void bspline_basis(float x, float bs[6]) {
    const float h = 2.0f / 3.0f;
    float g[10];
#pragma unroll
    for (int i = 0; i < 10; ++i) g[i] = (float)(i - 3) * h - 1.0f;
    float b[9];
#pragma unroll
    for (int i = 0; i < 9; ++i) b[i] = (x >= g[i] && x < g[i + 1]) ? 1.0f : 0.0f;
#pragma unroll
    for (int j = 1; j <= 3; ++j) {
        const float inv_d = 1.0f / ((float)j * h);
#pragma unroll
        for (int i = 0; i + j < 9; ++i) {
            float left  = (x - g[i]) * inv_d;
            float right = (g[i + j + 1] - x) * inv_d;
            b[i] = left * b[i] + right * b[i + 1];
        }
    }
#pragma unroll
    for (int i = 0; i < 6; ++i) bs[i] = b[i];
}

// Device-scope global barrier (all blocks resident by construction).
__device__ __forceinline__ void global_barrier(unsigned* bar, int idx, unsigned nblk) {
    __threadfence();                       // release: L2 writeback (sc1)
    __syncthreads();
    if (threadIdx.x == 0) {
        __hip_atomic_fetch_add(&bar[idx], 1u, __ATOMIC_RELEASE, __HIP_MEMORY_SCOPE_AGENT);
        while (__hip_atomic_load(&bar[idx], __ATOMIC_ACQUIRE, __HIP_MEMORY_SCOPE_AGENT) < nblk)
            __builtin_amdgcn_s_sleep(1);
    }
    __syncthreads();
    __threadfence();                       // acquire: invalidate stale L1/L2
}

// ---- conv+pool phase body (r8-proven), no returns; `tile` = virtual block.
// x: [B,C,H,W]; wrec: [C*9, O, 8] fused (tap-major); out: [B,O,H/2,W/2].
template <int C, int O, int GO, int H, int W, int VS, int OS, int FS, int NT>
__device__ __forceinline__ void conv_phase(
        const float* __restrict__ x,
        const float* __restrict__ wrec,
        float* __restrict__ out,
        unsigned char* s_mem,
        const int tid, const int tile) {
    constexpr int PH = H / 2, PW = W / 2;
    constexpr int PR = PH / VS;            // pooled rows per block
    constexpr int R  = 2 * PR + 2;         // input tile rows (incl. halo)
    constexpr int TC = W + 2;              // input tile cols (incl. halo)
    constexpr int CP = TC / 2;             // cols per parity plane
    constexpr int F  = C * 9;
    constexpr int PPB = PR * PW;           // pooled pixels per block
    constexpr int OPB = O / OS;            // output channels per block
    constexpr int NOG = OPB / GO;
    constexpr int CS = C / FS;             // channels per f-slice
    constexpr int CPLANE = R * 2 * CP;     // records per channel plane
    constexpr int HALF = C * CPLANE;       // records in act arena
    static_assert(NT == NOG * FS * PPB, "thread mapping");
    static_assert(FS * CS == C, "channel split");
    static_assert(NOG * GO == OPB && OPB * OS == O, "o split");
    static_assert(HALF * 28 <= 51408, "act fits arena");
    static_assert(FS == 1 || NT * GO * 16 <= 51408, "red fits arena");

    float4* s_lo = (float4*)s_mem;
    W3*     s_hi = (W3*)(s_mem + (size_t)HALF * 16);

    const int b   = tile / (VS * OS);
    const int rem = tile % (VS * OS);
    const int v   = rem / OS;
    const int osb = rem % OS;
    const int r0 = v * (2 * PR) - 1;       // global row of tile row 0

    __syncthreads();                       // prior phase/iter LDS reads done

    // ---- Stage: zero-padded x -> [silu, b0..b5] records in LDS
    const float* xb = x + (size_t)b * C * H * W;
    for (int i = tid; i < C * R * TC; i += NT) {
        int cc  = i / (R * TC);
        int rr  = (i / TC) % R;
        int col = i % TC;
        int gr = r0 + rr, gc = col - 1;
        float val = 0.0f;
        if ((unsigned)gr < (unsigned)H && (unsigned)gc < (unsigned)W)
            val = xb[(cc * H + gr) * W + gc];
        float silu = val / (1.0f + __expf(-val));
        float bs[6];
        bspline_basis(val, bs);
        int idx = ((cc * R + rr) * 2 + (col & 1)) * CP + (col >> 1);
        s_lo[idx] = make_float4(silu, bs[0], bs[1], bs[2]);
        W3 t; t.x = bs[3]; t.y = bs[4]; t.z = bs[5];
        s_hi[idx] = t;
    }
    __syncthreads();

    // ---- Thread mapping
    const int px = tid % PPB;
    const int fh = (tid / PPB) % FS;
    const int og = tid / (PPB * FS);
    const int phl = px / PW, pw = px % PW;
    const int o0 = osb * OPB + og * GO;

    float acc[GO][4];
#pragma unroll
    for (int g = 0; g < GO; ++g)
#pragma unroll
        for (int p = 0; p < 4; ++p) acc[g][p] = 0.f;

    const int pbase = (2 * phl) * (2 * CP) + pw;

#pragma unroll 1
    for (int cc = 0; cc < CS; ++cc) {
        const int c = fh * CS + cc;
        const float4* plo = s_lo + c * CPLANE;
        const W3*     phi = s_hi + c * CPLANE;
#pragma unroll 1
        for (int ky = 0; ky < 3; ++ky) {
#pragma unroll 1
            for (int kx = 0; kx < 3; ++kx) {
                const int f = c * 9 + ky * 3 + kx;
                const float4* wp = (const float4*)wrec + (size_t)(f * O + o0) * 2;
                float4 wl[GO];
                float  whx[GO], why[GO], whz[GO];
#pragma unroll
                for (int g = 0; g < GO; ++g) {
                    wl[g] = wp[g * 2];
                    float4 hv = wp[g * 2 + 1];
                    whx[g] = hv.x; why[g] = hv.y; whz[g] = hv.z;
                }
#pragma unroll
                for (int dy = 0; dy < 2; ++dy) {
#pragma unroll
                    for (int dx = 0; dx < 2; ++dx) {
                        const int s = dx + kx;
                        const int off = pbase + ((dy + ky) * 2 + (s & 1)) * CP + (s >> 1);
                        float4 lo = plo[off];
                        W3     hi = phi[off];
#pragma unroll
                        for (int g = 0; g < GO; ++g) {
                            acc[g][dy * 2 + dx] +=
                                lo.x * wl[g].x + lo.y * wl[g].y + lo.z * wl[g].z +
                                lo.w * wl[g].w + hi.x * whx[g] + hi.y * why[g] +
                                hi.z * whz[g];
                        }
                    }
                }
            }
        }
    }

    const int phg = v * PR + phl;

    if (FS > 1) {
        // f-split reduction; reduce buffer aliases the act arena.
        float4* s_red = (float4*)s_mem;
        __syncthreads();                   // act reads done before overwrite
#pragma unroll
        for (int g = 0; g < GO; ++g)
            s_red[g * NT + tid] = make_float4(acc[g][0], acc[g][1], acc[g][2], acc[g][3]);
        __syncthreads();
        if (fh == 0) {
#pragma unroll
            for (int fq = 1; fq < FS; ++fq)
#pragma unroll
                for (int g = 0; g < GO; ++g) {
                    float4 t = s_red[g * NT + tid + fq * PPB];
                    acc[g][0] += t.x; acc[g][1] += t.y; acc[g][2] += t.z; acc[g][3] += t.w;
                }
#pragma unroll
            for (int g = 0; g < GO; ++g) {
                float m = fmaxf(fmaxf(acc[g][0], acc[g][1]), fmaxf(acc[g][2], acc[g][3]));
                out[(((size_t)b * O + o0 + g) * PH + phg) * PW + pw] = m;
            }
        }
    } else {
#pragma unroll
        for (int g = 0; g < GO; ++g) {
            float m = fmaxf(fmaxf(acc[g][0], acc[g][1]), fmaxf(acc[g][2], acc[g][3]));
            out[(((size_t)b * O + o0 + g) * PH + phg) * PW + pw] = m;
        }
    }
}

// ---- One regular kernel: prep -> L1 -> L2 -> L3 -> linear, global barriers.
__global__ __launch_bounds__(NTHR, 2) void mega_kan(
        const float* __restrict__ x,
        const float* __restrict__ bw1, const float* __restrict__ sw1, const float* __restrict__ sc1,
        const float* __restrict__ bw2, const float* __restrict__ sw2, const float* __restrict__ sc2,
        const float* __restrict__ bw3, const float* __restrict__ sw3, const float* __restrict__ sc3,
        const float* __restrict__ lin_w, const float* __restrict__ lin_b,
        float* __restrict__ out,
        float* __restrict__ w1, float* __restrict__ w2, float* __restrict__ w3,
        float* __restrict__ h1, float* __restrict__ h2, float* __restrict__ h3,
        unsigned* __restrict__ bar) {
    __shared__ alignas(16) unsigned char s_mem[51408];  // max phase arena (L1)
    const int tid = threadIdx.x;
    const int bid = blockIdx.x;

    // ---- Phase 0: fuse {base_w, spline_w*scaler} -> tap-major [F][O][8]
    {
        int i = bid * NTHR + tid;
        const float *bw, *sw, *sc;
        float* dst;
        int j = 0, O = 0, F = 0;
        bool act = true;
        if (i < 216)       { bw = bw1; sw = sw1; sc = sc1; dst = w1; j = i;        O = 8;  F = 27;  }
        else if (i < 1368) { bw = bw2; sw = sw2; sc = sc2; dst = w2; j = i - 216;  O = 16; F = 72;  }
        else if (i < 5976) { bw = bw3; sw = sw3; sc = sc3; dst = w3; j = i - 1368; O = 32; F = 144; }
        else               { bw = bw1; sw = sw1; sc = sc1; dst = w1; act = false; }
        if (act) {
            int o = j / F, fi = j % F;     // input is [O,F] row-major
            float s = sc[j];
            float4* dq = (float4*)(dst + (size_t)(fi * O + o) * 8);
            dq[0] = make_float4(bw[j], sw[j * 6 + 0] * s, sw[j * 6 + 1] * s, sw[j * 6 + 2] * s);
            dq[1] = make_float4(sw[j * 6 + 3] * s, sw[j * 6 + 4] * s, sw[j * 6 + 5] * s, 0.0f);
        }
    }
    global_barrier(bar, 0, NBLK);

    // ---- Phase 1: L1 [256,3,32,32] -> [256,8,16,16]; GO=2, FS=1, VS=2.
#pragma unroll 1
    for (int it = 0; it < 2; ++it)
        conv_phase<3, 8, 2, 32, 32, 2, 1, 1, NTHR>(x, w1, h1, s_mem, tid, bid + NBLK * it);
    global_barrier(bar, 1, NBLK);

    // ---- Phase 2: L2 [256,8,16,16] -> [256,16,8,8]; GO=4, FS=4, VS=2.
#pragma unroll 1
    for (int it = 0; it < 2; ++it)
        conv_phase<8, 16, 4, 16, 16, 2, 1, 4, NTHR>(h1, w2, h2, s_mem, tid, bid + NBLK * it);
    global_barrier(bar, 2, NBLK);

    // ---- Phase 3: L3 [256,16,8,8] -> [256,32,4,4]; GO=4, FS=8, OS=2.
#pragma unroll 1
    for (int it = 0; it < 2; ++it)
        conv_phase<16, 32, 4, 8, 8, 1, 2, 8, NTHR>(h2, w3, h3, s_mem, tid, bid + NBLK * it);
    global_barrier(bar, 3, NBLK);

    // ---- Phase 4: linear out[n,o] = dot(h3[n,:512], lin_w[o,:512]) + b[o]
    {
        int idx = bid * NTHR + tid;
        if (idx < BATCH * 100) {
            int o = idx % 100;
            int n = idx / 100;
            const float4* hp = (const float4*)(h3 + (size_t)n * 512);
            const float4* wp = (const float4*)(lin_w + (size_t)o * 512);
            float acc = 0.f;
#pragma unroll 4
            for (int i = 0; i < 128; ++i) {
                float4 a = hp[i];
                float4 b = wp[i];
                acc += a.x * b.x + a.y * b.y + a.z * b.z + a.w * b.w;
            }
            out[idx] = acc + lin_b[o];
        }
    }
}

extern "C" void kernel_launch(void* const* d_in, const int* in_sizes, int n_in,
                              void* d_out, int out_size, void* d_ws, size_t ws_size,
                              hipStream_t stream) {
    const float* x     = (const float*)d_in[0];
    const float* c1_bw = (const float*)d_in[1];
    const float* c1_sw = (const float*)d_in[2];
    const float* c1_sc = (const float*)d_in[3];
    const float* c2_bw = (const float*)d_in[4];
    const float* c2_sw = (const float*)d_in[5];
    const float* c2_sc = (const float*)d_in[6];
    const float* c3_bw = (const float*)d_in[7];
    const float* c3_sw = (const float*)d_in[8];
    const float* c3_sc = (const float*)d_in[9];
    const float* lin_w = (const float*)d_in[10];
    const float* lin_b = (const float*)d_in[11];
    float* out = (float*)d_out;

    float* ws = (float*)d_ws;
    float* h1 = ws;                 // 256*8*16*16  = 524288
    float* h2 = h1 + 524288;        // 256*16*8*8   = 262144
    float* h3 = h2 + 262144;        // 256*32*4*4   = 131072
    float* w1 = h3 + 131072;        // 216*8  = 1728
    float* w2 = w1 + 1728;          // 1152*8 = 9216
    float* w3 = w2 + 9216;          // 4608*8 = 36864
    unsigned* bar = (unsigned*)(w3 + 36864);   // 16 counters (64 B)
    // total < 1M floats = 3.9 MB of workspace

    // Zero barrier counters (graph-capturable async memset on the stream).
    hipMemsetAsync(bar, 0, 64, stream);

    mega_kan<<<NBLK, NTHR, 0, stream>>>(
        x,
        c1_bw, c1_sw, c1_sc,
        c2_bw, c2_sw, c2_sc,
        c3_bw, c3_sw, c3_sc,
        lin_w, lin_b,
        out,
        w1, w2, w3, h1, h2, h3, bar);
}

// Round 6
// 155.216 us; speedup vs baseline: 3.2599x; 3.2599x over previous
//
#include <hip/hip_runtime.h>
#include <math.h>

// ---------------------------------------------------------------------------
// KAN-Conv CIFAR net on gfx950, round 11.
// r10 (fused mega-kernel + global barriers) = 450us vs 164us for 5 launches:
// resident fusion loses occupancy (8 vs 16-24 waves/CU) and cache warmth
// (per-thread threadfence L2 writeback). Launch gaps are bounded small.
// This round: r8 structure (164us) minus cheap overheads:
//  (1) prep_weights launch eliminated: L1 builds its own w1 in LDS (r5's
//      proven WLDS win, kills L1 per-tap global weight loads); L1 blocks 0..7
//      prep w2/w3 to global inline (launch boundary = visibility barrier).
//  (2) linear rewritten wave-cooperative: block per n, h3[n] in LDS, wave
//      owns 25 outputs, w[o] rows read COALESCED (lane l -> float4 l, l+64),
//      shfl_xor reduce. Old version fanned every load to 64 cache lines.
// Conv bodies/configs are r8-verbatim otherwise.
// ---------------------------------------------------------------------------

#define BATCH 256

struct W3 { float x, y, z; };   // packed 12-byte LDS record

__device__ __forceinline__ void bspline_basis(float x, float bs[6]) {
    const float h = 2.0f / 3.0f;
    float g[10];
#pragma unroll
    for (int i = 0; i < 10; ++i) g[i] = (float)(i - 3) * h - 1.0f;
    float b[9];
#pragma unroll
    for (int i = 0; i < 9; ++i) b[i] = (x >= g[i] && x < g[i + 1]) ? 1.0f : 0.0f;
#pragma unroll
    for (int j = 1; j <= 3; ++j) {
        const float inv_d = 1.0f / ((float)j * h);
#pragma unroll
        for (int i = 0; i + j < 9; ++i) {
            float left  = (x - g[i]) * inv_d;
            float right = (g[i + j + 1] - x) * inv_d;
            b[i] = left * b[i] + right * b[i + 1];
        }
    }
#pragma unroll
    for (int i = 0; i < 6; ++i) bs[i] = b[i];
}

// Fused: basis precompute (LDS) + KAN conv3x3(pad1) + maxpool2.
// x: [B,C,H,W]; wrec: [C*9, O, 8] fused (tap-major); out: [B,O,H/2,W/2].
// VS: vertical split of pooled rows across blocks. OS: output-channel split
// across blocks. FS: channel split within block (LDS-reduced).
// WLDS: build this layer's fused weights in LDS from raw (bw,sw,sc).
// PREP: first blocks also fuse the OTHER layers' weights to global.
template <int C, int O, int GO, int H, int W, int VS, int OS, int FS, int NT,
          int MINW, int WLDS, int PREP>
__global__ __launch_bounds__(NT, MINW) void kan_conv_pool(
        const float* __restrict__ x,
        const float* __restrict__ wrec,
        const float* __restrict__ rbw, const float* __restrict__ rsw, const float* __restrict__ rsc,
        const float* __restrict__ p2bw, const float* __restrict__ p2sw, const float* __restrict__ p2sc,
        const float* __restrict__ p3bw, const float* __restrict__ p3sw, const float* __restrict__ p3sc,
        float* __restrict__ w2dst, float* __restrict__ w3dst,
        float* __restrict__ out) {
    constexpr int PH = H / 2, PW = W / 2;
    constexpr int PR = PH / VS;            // pooled rows per block
    constexpr int R  = 2 * PR + 2;         // input tile rows (incl. halo)
    constexpr int TC = W + 2;              // input tile cols (incl. halo)
    constexpr int CP = TC / 2;             // cols per parity plane
    constexpr int F  = C * 9;
    constexpr int PPB = PR * PW;           // pooled pixels per block
    constexpr int OPB = O / OS;            // output channels per block
    constexpr int NOG = OPB / GO;
    constexpr int CS = C / FS;             // channels per f-slice
    constexpr int CPLANE = R * 2 * CP;     // records per channel plane
    constexpr int HALF = C * CPLANE;       // records in act arena
    static_assert(NT == NOG * FS * PPB, "thread mapping");
    static_assert(FS * CS == C, "channel split");
    static_assert(NOG * GO == OPB && OPB * OS == O, "o split");

    // Act arena: float4 lo[HALF] then W3 hi[HALF]; FS-reduction buffer
    // aliases the arena. LDS weights (WLDS) live in separate arrays.
    constexpr int ACT_BYTES = HALF * 28;
    constexpr int RED_BYTES = (FS > 1) ? NT * GO * 16 : 0;
    constexpr int ARENA = ACT_BYTES > RED_BYTES ? ACT_BYTES : RED_BYTES;
    static_assert(RED_BYTES <= ARENA, "red fits");
    __shared__ alignas(16) unsigned char s_mem[ARENA];
    float4* s_lo = (float4*)s_mem;
    W3*     s_hi = (W3*)(s_mem + (size_t)HALF * 16);
    constexpr int NWR = WLDS ? O * F : 1;
    __shared__ float4 s_wlo[NWR];
    __shared__ W3     s_whi[NWR];

    const int tid = threadIdx.x;
    const int bid = blockIdx.x;

    // ---- Inline prep of other layers' fused weights (first blocks only).
    if (PREP) {
        int i = bid * NT + tid;
        if (i < 5760) {
            const float *bw, *sw, *sc;
            float* dst;
            int j, OO, FF;
            if (i < 1152) { bw = p2bw; sw = p2sw; sc = p2sc; dst = w2dst; j = i;        OO = 16; FF = 72;  }
            else          { bw = p3bw; sw = p3sw; sc = p3sc; dst = w3dst; j = i - 1152; OO = 32; FF = 144; }
            int o = j / FF, fi = j % FF;   // input [O,F] row-major -> tap-major out
            float s = sc[j];
            float4* dq = (float4*)(dst + (size_t)(fi * OO + o) * 8);
            dq[0] = make_float4(bw[j], sw[j * 6 + 0] * s, sw[j * 6 + 1] * s, sw[j * 6 + 2] * s);
            dq[1] = make_float4(sw[j * 6 + 3] * s, sw[j * 6 + 4] * s, sw[j * 6 + 5] * s, 0.0f);
        }
    }

    // ---- Own-layer fused weights into LDS (tap-major r = f*O + o).
    if (WLDS) {
        for (int j = tid; j < O * F; j += NT) {
            int o = j / F, fi = j % F;
            float s = rsc[j];
            int r = fi * O + o;
            s_wlo[r] = make_float4(rbw[j], rsw[j * 6 + 0] * s, rsw[j * 6 + 1] * s, rsw[j * 6 + 2] * s);
            W3 t; t.x = rsw[j * 6 + 3] * s; t.y = rsw[j * 6 + 4] * s; t.z = rsw[j * 6 + 5] * s;
            s_whi[r] = t;
        }
    }

    const int b   = bid / (VS * OS);
    const int rem = bid % (VS * OS);
    const int v   = rem / OS;
    const int osb = rem % OS;
    const int r0 = v * (2 * PR) - 1;       // global row of tile row 0

    // ---- Stage: zero-padded x -> [silu, b0..b5] records in LDS
    const float* xb = x + (size_t)b * C * H * W;
    for (int i = tid; i < C * R * TC; i += NT) {
        int cc  = i / (R * TC);
        int rr  = (i / TC) % R;
        int col = i % TC;
        int gr = r0 + rr, gc = col - 1;
        float val = 0.0f;
        if ((unsigned)gr < (unsigned)H && (unsigned)gc < (unsigned)W)
            val = xb[(cc * H + gr) * W + gc];
        float silu = val / (1.0f + __expf(-val));
        float bs[6];
        bspline_basis(val, bs);
        int idx = ((cc * R + rr) * 2 + (col & 1)) * CP + (col >> 1);
        s_lo[idx] = make_float4(silu, bs[0], bs[1], bs[2]);
        W3 t; t.x = bs[3]; t.y = bs[4]; t.z = bs[5];
        s_hi[idx] = t;
    }
    __syncthreads();

    // ---- Thread mapping
    const int px = tid % PPB;
    const int fh = (tid / PPB) % FS;
    const int og = tid / (PPB * FS);
    const int phl = px / PW, pw = px % PW;
    const int o0 = osb * OPB + og * GO;

    float acc[GO][4];
#pragma unroll
    for (int g = 0; g < GO; ++g)
#pragma unroll
        for (int p = 0; p < 4; ++p) acc[g][p] = 0.f;

    const int pbase = (2 * phl) * (2 * CP) + pw;

#pragma unroll 1
    for (int cc = 0; cc < CS; ++cc) {
        const int c = fh * CS + cc;
        const float4* plo = s_lo + c * CPLANE;
        const W3*     phi = s_hi + c * CPLANE;
#pragma unroll 1
        for (int ky = 0; ky < 3; ++ky) {
#pragma unroll 1
            for (int kx = 0; kx < 3; ++kx) {
                const int f = c * 9 + ky * 3 + kx;
                float4 wl[GO];
                float  whx[GO], why[GO], whz[GO];
                if (WLDS) {
                    const int rb = f * O + o0;
#pragma unroll
                    for (int g = 0; g < GO; ++g) {
                        wl[g] = s_wlo[rb + g];
                        W3 t = s_whi[rb + g];
                        whx[g] = t.x; why[g] = t.y; whz[g] = t.z;
                    }
                } else {
                    const float4* wp = (const float4*)wrec + (size_t)(f * O + o0) * 2;
#pragma unroll
                    for (int g = 0; g < GO; ++g) {
                        wl[g] = wp[g * 2];
                        float4 hv = wp[g * 2 + 1];
                        whx[g] = hv.x; why[g] = hv.y; whz[g] = hv.z;
                    }
                }
#pragma unroll
                for (int dy = 0; dy < 2; ++dy) {
#pragma unroll
                    for (int dx = 0; dx < 2; ++dx) {
                        const int s = dx + kx;
                        const int off = pbase + ((dy + ky) * 2 + (s & 1)) * CP + (s >> 1);
                        float4 lo = plo[off];
                        W3     hi = phi[off];
#pragma unroll
                        for (int g = 0; g < GO; ++g) {
                            acc[g][dy * 2 + dx] +=
                                lo.x * wl[g].x + lo.y * wl[g].y + lo.z * wl[g].z +
                                lo.w * wl[g].w + hi.x * whx[g] + hi.y * why[g] +
                                hi.z * whz[g];
                        }
                    }
                }
            }
        }
    }

    const int phg = v * PR + phl;

    if (FS > 1) {
        // f-split reduction; reduce buffer aliases the act arena.
        float4* s_red = (float4*)s_mem;
        __syncthreads();                   // act reads done before overwrite
#pragma unroll
        for (int g = 0; g < GO; ++g)
            s_red[g * NT + tid] = make_float4(acc[g][0], acc[g][1], acc[g][2], acc[g][3]);
        __syncthreads();
        if (fh != 0) return;
#pragma unroll
        for (int fq = 1; fq < FS; ++fq)
#pragma unroll
            for (int g = 0; g < GO; ++g) {
                float4 t = s_red[g * NT + tid + fq * PPB];
                acc[g][0] += t.x; acc[g][1] += t.y; acc[g][2] += t.z; acc[g][3] += t.w;
            }
#pragma unroll
        for (int g = 0; g < GO; ++g) {
            float m = fmaxf(fmaxf(acc[g][0], acc[g][1]), fmaxf(acc[g][2], acc[g][3]));
            out[(((size_t)b * O + o0 + g) * PH + phg) * PW + pw] = m;
        }
    } else {
#pragma unroll
        for (int g = 0; g < GO; ++g) {
            float m = fmaxf(fmaxf(acc[g][0], acc[g][1]), fmaxf(acc[g][2], acc[g][3]));
            out[(((size_t)b * O + o0 + g) * PH + phg) * PW + pw] = m;
        }
    }
}

// Wave-cooperative linear: block per n; h3[n] staged in LDS; wave wv owns
// outputs o = wv*25+i; w[o] rows read coalesced (lane l -> float4 l, l+64);
// dot reduced via shfl_xor.
__global__ __launch_bounds__(256) void linear_coop(const float* __restrict__ h,
                                                   const float* __restrict__ w,
                                                   const float* __restrict__ bias,
                                                   float* __restrict__ out) {
    const int n = blockIdx.x;
    const int tid = threadIdx.x;
    const int lane = tid & 63;
    const int wv = tid >> 6;

    __shared__ float4 s_h[128];            // h3[n] as 128 float4
    if (tid < 128) s_h[tid] = ((const float4*)(h + (size_t)n * 512))[tid];
    __syncthreads();

    const float4 h0 = s_h[lane];
    const float4 h1 = s_h[lane + 64];

#pragma unroll 1
    for (int i = 0; i < 25; ++i) {
        const int o = wv * 25 + i;
        const float4* wr = (const float4*)(w + (size_t)o * 512);
        float4 w0 = wr[lane];
        float4 w1 = wr[lane + 64];
        float p = w0.x * h0.x + w0.y * h0.y + w0.z * h0.z + w0.w * h0.w
                + w1.x * h1.x + w1.y * h1.y + w1.z * h1.z + w1.w * h1.w;
        p += __shfl_xor(p, 32);
        p += __shfl_xor(p, 16);
        p += __shfl_xor(p, 8);
        p += __shfl_xor(p, 4);
        p += __shfl_xor(p, 2);
        p += __shfl_xor(p, 1);
        if (lane == 0) out[(size_t)n * 100 + o] = p + bias[o];
    }
}

extern "C" void kernel_launch(void* const* d_in, const int* in_sizes, int n_in,
                              void* d_out, int out_size, void* d_ws, size_t ws_size,
                              hipStream_t stream) {
    const float* x     = (const float*)d_in[0];
    const float* c1_bw = (const float*)d_in[1];
    const float* c1_sw = (const float*)d_in[2];
    const float* c1_sc = (const float*)d_in[3];
    const float* c2_bw = (const float*)d_in[4];
    const float* c2_sw = (const float*)d_in[5];
    const float* c2_sc = (const float*)d_in[6];
    const float* c3_bw = (const float*)d_in[7];
    const float* c3_sw = (const float*)d_in[8];
    const float* c3_sc = (const float*)d_in[9];
    const float* lin_w = (const float*)d_in[10];
    const float* lin_b = (const float*)d_in[11];
    float* out = (float*)d_out;

    float* ws = (float*)d_ws;
    float* h1 = ws;                 // 256*8*16*16  = 524288
    float* h2 = h1 + 524288;        // 256*16*8*8   = 262144
    float* h3 = h2 + 262144;        // 256*32*4*4   = 131072
    float* w2 = h3 + 131072;        // 1152*8 = 9216
    float* w3 = w2 + 9216;          // 4608*8 = 36864
    // total < 1M floats = 3.9 MB of workspace

    // L1: [256,3,32,32] -> [256,8,16,16]; GO=4, FS=3, NT=768, WLDS + inline
    // prep of w2/w3 (blocks 0..7). 512 blocks.
    kan_conv_pool<3, 8, 4, 32, 32, 2, 1, 3, 768, 4, 1, 1><<<512, 768, 0, stream>>>(
        x, nullptr,
        c1_bw, c1_sw, c1_sc,
        c2_bw, c2_sw, c2_sc,
        c3_bw, c3_sw, c3_sc,
        w2, w3, h1);
    // L2: [256,8,16,16] -> [256,16,8,8]; GO=4, FS=4, NT=512. 512 blocks.
    kan_conv_pool<8, 16, 4, 16, 16, 2, 1, 4, 512, 4, 0, 0><<<512, 512, 0, stream>>>(
        h1, w2,
        nullptr, nullptr, nullptr,
        nullptr, nullptr, nullptr,
        nullptr, nullptr, nullptr,
        nullptr, nullptr, h2);
    // L3: [256,16,8,8] -> [256,32,4,4]; OS=2, GO=4, FS=8, NT=512. 512 blocks.
    kan_conv_pool<16, 32, 4, 8, 8, 1, 2, 8, 512, 4, 0, 0><<<512, 512, 0, stream>>>(
        h2, w3,
        nullptr, nullptr, nullptr,
        nullptr, nullptr, nullptr,
        nullptr, nullptr, nullptr,
        nullptr, nullptr, h3);
    // Linear: [256,512] @ [100,512]^T + b; block per n, coalesced w reads.
    linear_coop<<<256, 256, 0, stream>>>(h3, lin_w, lin_b, out);
}